// Round 1
// baseline (272.496 us; speedup 1.0000x reference)
//
#include <hip/hip_runtime.h>
#include <math.h>

#define H 2048
#define E 64
#define ROWS 8
#define ST 2052   // LDS row stride (pad 4 floats: keeps 16B align, breaks pow2 bank stride)

__device__ __forceinline__ float sclamp50(float v) {
    // nan -> 0, +/-inf -> +/-50, clip to [-50, 50]
    if (v != v) v = 0.f;
    return fminf(fmaxf(v, -50.f), 50.f);
}

__global__ __launch_bounds__(256) void transpose_w(const float* __restrict__ W,
                                                   float* __restrict__ Wt) {
    int o = blockIdx.x * 256 + threadIdx.x;   // o = k*64 + e
    int k = o >> 6;
    int e = o & 63;
    Wt[o] = W[e * H + k];                     // coalesced writes
}

__global__ __launch_bounds__(256) void router_kernel(
    const float* __restrict__ X, const float* __restrict__ lnw,
    const float* __restrict__ lnb, const float* __restrict__ Wt,
    float* __restrict__ out, int nRows)
{
    __shared__ float xs[ROWS * ST];          // 65,664 B
    __shared__ float C[4 * ROWS * E];        // 8,192 B  (per-wave GEMM partials -> logits)
    __shared__ float mu_s[ROWS], rs_s[ROWS];

    const int t    = threadIdx.x;
    const int lane = t & 63;
    const int wv   = t >> 6;                  // wave id 0..3
    const long rowBase = (long)blockIdx.x * ROWS;
    const long iOff = (long)nRows * 2;        // indices region offset
    const long lOff = (long)nRows * 4;        // logits region offset

    // ---- Phase 1: load 8 rows (64 KB) global -> LDS, coalesced float4 ----
    const float4* Xg = (const float4*)(X + rowBase * H);
    #pragma unroll
    for (int i = 0; i < 16; ++i) {
        int f4 = t + i * 256;                 // 0..4095
        int r  = f4 >> 9;                     // 512 float4 per row
        int c  = (f4 & 511) << 2;
        float4 v = Xg[f4];
        *(float4*)&xs[r * ST + c] = v;
    }
    __syncthreads();

    // ---- Phase 2: LN stats, wave wv handles rows 2wv, 2wv+1 ----
    #pragma unroll
    for (int rr = 0; rr < 2; ++rr) {
        int r = wv * 2 + rr;
        float s = 0.f, q = 0.f;
        #pragma unroll
        for (int j = 0; j < 8; ++j) {
            float4 v = *(float4*)&xs[r * ST + ((lane + j * 64) << 2)];
            s += v.x + v.y + v.z + v.w;
            q += v.x * v.x + v.y * v.y + v.z * v.z + v.w * v.w;
        }
        #pragma unroll
        for (int d = 1; d < 64; d <<= 1) {
            s += __shfl_xor(s, d);
            q += __shfl_xor(q, d);
        }
        if (lane == 0) {
            float mu  = s * (1.f / H);
            float var = q * (1.f / H) - mu * mu;
            mu_s[r] = mu;
            rs_s[r] = rsqrtf(var + 1e-5f);
        }
    }
    __syncthreads();

    // ---- Phase 3: normalize + safe_clamp in LDS ----
    #pragma unroll
    for (int i = 0; i < 16; ++i) {
        int f4 = t + i * 256;
        int r  = f4 >> 9;
        int c  = (f4 & 511) << 2;
        float mu = mu_s[r], rs = rs_s[r];
        float4 v = *(float4*)&xs[r * ST + c];
        float4 w = *(const float4*)&lnw[c];
        float4 b = *(const float4*)&lnb[c];
        v.x = sclamp50((v.x - mu) * rs * w.x + b.x);
        v.y = sclamp50((v.y - mu) * rs * w.y + b.y);
        v.z = sclamp50((v.z - mu) * rs * w.z + b.z);
        v.w = sclamp50((v.w - mu) * rs * w.w + b.w);
        *(float4*)&xs[r * ST + c] = v;
    }
    __syncthreads();

    // ---- Phase 4: GEMM. thread = (eg: 4 experts, rg: 4 rows, kc: 256-wide K chunk) ----
    const int eg = t & 15;
    const int rg = (t >> 4) & 1;
    const int kc = t >> 5;
    const int e0 = eg * 4, r0 = rg * 4, k0 = kc * 256;

    float acc[4][4] = {};
    for (int k = k0; k < k0 + 256; k += 4) {
        float4 xv[4], wvv[4];
        #pragma unroll
        for (int i = 0; i < 4; ++i)
            xv[i] = *(float4*)&xs[(r0 + i) * ST + k];
        #pragma unroll
        for (int kk = 0; kk < 4; ++kk)
            wvv[kk] = *(const float4*)&Wt[(k + kk) * E + e0];
        #pragma unroll
        for (int kk = 0; kk < 4; ++kk) {
            float w0 = wvv[kk].x, w1 = wvv[kk].y, w2 = wvv[kk].z, w3 = wvv[kk].w;
            #pragma unroll
            for (int i = 0; i < 4; ++i) {
                float xi = ((const float*)&xv[i])[kk];
                acc[i][0] = fmaf(xi, w0, acc[i][0]);
                acc[i][1] = fmaf(xi, w1, acc[i][1]);
                acc[i][2] = fmaf(xi, w2, acc[i][2]);
                acc[i][3] = fmaf(xi, w3, acc[i][3]);
            }
        }
    }
    // reduce the kc pair within each wave (lanes differ in bit 5)
    #pragma unroll
    for (int i = 0; i < 4; ++i)
        #pragma unroll
        for (int j = 0; j < 4; ++j)
            acc[i][j] += __shfl_xor(acc[i][j], 32);
    if ((t & 32) == 0) {
        #pragma unroll
        for (int i = 0; i < 4; ++i) {
            float4 vv = make_float4(acc[i][0], acc[i][1], acc[i][2], acc[i][3]);
            *(float4*)&C[(wv * ROWS + r0 + i) * E + e0] = vv;
        }
    }
    __syncthreads();

    // ---- Phase 5: cross-wave reduce, clip, write logits ----
    {
        int r   = t >> 5;             // 0..7
        int e0b = (t & 31) * 2;       // 0..62 step 2
        float2 s = make_float2(0.f, 0.f);
        #pragma unroll
        for (int w2 = 0; w2 < 4; ++w2) {
            float2 v = *(float2*)&C[(w2 * ROWS + r) * E + e0b];
            s.x += v.x; s.y += v.y;
        }
        s.x = fminf(fmaxf(s.x, -10.f), 10.f);
        s.y = fminf(fmaxf(s.y, -10.f), 10.f);
        long rg_ = rowBase + r;
        *(float2*)&out[lOff + rg_ * E + e0b] = s;
        *(float2*)&C[r * E + e0b] = s;        // stash clipped logits in C[0][r][*]
    }
    __syncthreads();

    // ---- Phase 6: softmax + top2 per row, wave wv handles rows 2wv, 2wv+1 ----
    #pragma unroll
    for (int rr = 0; rr < 2; ++rr) {
        int r = wv * 2 + rr;
        float l = C[r * E + lane];
        float m = l;
        #pragma unroll
        for (int d = 1; d < 64; d <<= 1) m = fmaxf(m, __shfl_xor(m, d));
        float p = __expf(l - m);
        float ssum = p;
        #pragma unroll
        for (int d = 1; d < 64; d <<= 1) ssum += __shfl_xor(ssum, d);
        float prob = fminf(fmaxf(p / ssum, 1e-4f), 1.0f);

        // top1 (max value, lowest index on tie)
        float v1 = prob; int i1 = lane;
        #pragma unroll
        for (int d = 1; d < 64; d <<= 1) {
            float ov = __shfl_xor(v1, d);
            int   oi = __shfl_xor(i1, d);
            if (ov > v1 || (ov == v1 && oi < i1)) { v1 = ov; i1 = oi; }
        }
        // top2: mask out i1, reduce again
        float v2 = (lane == i1) ? -1.f : prob; int i2 = lane;
        #pragma unroll
        for (int d = 1; d < 64; d <<= 1) {
            float ov = __shfl_xor(v2, d);
            int   oi = __shfl_xor(i2, d);
            if (ov > v2 || (ov == v2 && oi < i2)) { v2 = ov; i2 = oi; }
        }
        if (lane == 0) {
            float ps = fmaxf(v1 + v2, 1e-4f);
            long rg_ = rowBase + r;
            out[rg_ * 2 + 0] = v1 / ps;
            out[rg_ * 2 + 1] = v2 / ps;
            out[iOff + rg_ * 2 + 0] = (float)i1;
            out[iOff + rg_ * 2 + 1] = (float)i2;
        }
    }
}

extern "C" void kernel_launch(void* const* d_in, const int* in_sizes, int n_in,
                              void* d_out, int out_size, void* d_ws, size_t ws_size,
                              hipStream_t stream) {
    const float* X   = (const float*)d_in[0];
    const float* lnw = (const float*)d_in[1];
    const float* lnb = (const float*)d_in[2];
    const float* W   = (const float*)d_in[3];
    float* outp = (float*)d_out;
    float* Wt   = (float*)d_ws;                 // 2048*64*4 = 512 KB scratch

    int N = in_sizes[0] / H;                    // 16384 rows

    transpose_w<<<(H * E) / 256, 256, 0, stream>>>(W, Wt);
    router_kernel<<<N / ROWS, 256, 0, stream>>>(X, lnw, lnb, Wt, outp, N);
}

// Round 2
// 268.610 us; speedup vs baseline: 1.0145x; 1.0145x over previous
//
#include <hip/hip_runtime.h>
#include <math.h>

#define H 2048
#define E 64
#define ROWS 8
#define ST 2052   // LDS row stride in floats (16B-aligned, breaks pow2 bank stride)

// ws layout (floats): Wt'[H*E] | csum[E] | bsum[E]
#define WS_WT   0
#define WS_CS   (H * E)
#define WS_BS   (H * E + E)

__global__ __launch_bounds__(256) void prep_transpose(const float* __restrict__ W,
        const float* __restrict__ lnw, float* __restrict__ Wt) {
    int o = blockIdx.x * 256 + threadIdx.x;   // o = k*64 + e
    int k = o >> 6, e = o & 63;
    Wt[o] = lnw[k] * W[e * H + k];            // coalesced writes, L2-cached reads
}

__global__ __launch_bounds__(256) void prep_sums(const float* __restrict__ W,
        const float* __restrict__ lnw, const float* __restrict__ lnb,
        float* __restrict__ csum, float* __restrict__ bsum) {
    __shared__ float rc[256], rb[256];
    int e = blockIdx.x, t = threadIdx.x;
    float cs = 0.f, bs = 0.f;
    #pragma unroll
    for (int j = 0; j < 8; ++j) {
        int k = t + j * 256;
        float w = W[e * H + k];               // coalesced
        cs += lnw[k] * w;
        bs += lnb[k] * w;
    }
    rc[t] = cs; rb[t] = bs;
    __syncthreads();
    for (int s = 128; s > 0; s >>= 1) {
        if (t < s) { rc[t] += rc[t + s]; rb[t] += rb[t + s]; }
        __syncthreads();
    }
    if (t == 0) { csum[e] = rc[0]; bsum[e] = rb[0]; }
}

__global__ __launch_bounds__(256) void router_kernel(
    const float* __restrict__ X, const float* __restrict__ Wt,
    const float* __restrict__ csum, const float* __restrict__ bsum,
    float* __restrict__ out, int nRows)
{
    __shared__ float xs[ROWS * ST];          // 65,664 B — RAW x rows (no LN applied)
    __shared__ float C[4 * ROWS * E];        // 8,192 B  — per-wave GEMM partials -> logits
    __shared__ float mu_s[ROWS], rs_s[ROWS];

    const int t    = threadIdx.x;
    const int lane = t & 63;
    const int wv   = t >> 6;                  // wave id 0..3
    const long rowBase = (long)blockIdx.x * ROWS;
    const long iOff = (long)nRows * 2;        // indices region offset
    const long lOff = (long)nRows * 4;        // logits region offset

    // ---- Phase 1: each wave loads its 2 rows coalesced, stats on the fly, one LDS write ----
    #pragma unroll
    for (int rr = 0; rr < 2; ++rr) {
        int r = wv * 2 + rr;
        const float4* src = (const float4*)(X + (rowBase + r) * H);
        float4 v[8];
        #pragma unroll
        for (int j = 0; j < 8; ++j) v[j] = src[lane + j * 64];
        float s = 0.f, q = 0.f;
        #pragma unroll
        for (int j = 0; j < 8; ++j) {
            s += v[j].x + v[j].y + v[j].z + v[j].w;
            q += v[j].x * v[j].x + v[j].y * v[j].y + v[j].z * v[j].z + v[j].w * v[j].w;
        }
        #pragma unroll
        for (int j = 0; j < 8; ++j)
            *(float4*)&xs[r * ST + ((lane + j * 64) << 2)] = v[j];
        #pragma unroll
        for (int d = 1; d < 64; d <<= 1) {
            s += __shfl_xor(s, d);
            q += __shfl_xor(q, d);
        }
        if (lane == 0) {
            float mu  = s * (1.f / H);
            float var = q * (1.f / H) - mu * mu;
            mu_s[r] = mu;
            rs_s[r] = rsqrtf(var + 1e-5f);
        }
    }
    __syncthreads();

    // ---- Phase 2: GEMM on RAW x. thread = (eg:4 experts, rg:4 rows, kc:256-wide K chunk) ----
    // Wt' prefetched one iteration (8 k) ahead in registers to hide L2 latency.
    const int eg = t & 15;
    const int rg = (t >> 4) & 1;
    const int kc = t >> 5;
    const int e0 = eg * 4, r0 = rg * 4, k0 = kc * 256;

    float acc[4][4] = {};
    float4 wA[4], wB[4];
    #pragma unroll
    for (int kk = 0; kk < 4; ++kk)
        wA[kk] = *(const float4*)&Wt[(k0 + kk) * E + e0];

    for (int k = k0; k < k0 + 256; k += 8) {
        // prefetch second half of this iteration
        #pragma unroll
        for (int kk = 0; kk < 4; ++kk)
            wB[kk] = *(const float4*)&Wt[(k + 4 + kk) * E + e0];

        float4 xv[4];
        #pragma unroll
        for (int i = 0; i < 4; ++i)
            xv[i] = *(float4*)&xs[(r0 + i) * ST + k];
        #pragma unroll
        for (int kk = 0; kk < 4; ++kk) {
            float w0 = wA[kk].x, w1 = wA[kk].y, w2 = wA[kk].z, w3 = wA[kk].w;
            #pragma unroll
            for (int i = 0; i < 4; ++i) {
                float xi = ((const float*)&xv[i])[kk];
                acc[i][0] = fmaf(xi, w0, acc[i][0]);
                acc[i][1] = fmaf(xi, w1, acc[i][1]);
                acc[i][2] = fmaf(xi, w2, acc[i][2]);
                acc[i][3] = fmaf(xi, w3, acc[i][3]);
            }
        }

        // prefetch first half of next iteration (clamped to avoid OOB on last iter)
        int kn = (k + 8 < k0 + 256) ? (k + 8) : k0;
        #pragma unroll
        for (int kk = 0; kk < 4; ++kk)
            wA[kk] = *(const float4*)&Wt[(kn + kk) * E + e0];

        #pragma unroll
        for (int i = 0; i < 4; ++i)
            xv[i] = *(float4*)&xs[(r0 + i) * ST + k + 4];
        #pragma unroll
        for (int kk = 0; kk < 4; ++kk) {
            float w0 = wB[kk].x, w1 = wB[kk].y, w2 = wB[kk].z, w3 = wB[kk].w;
            #pragma unroll
            for (int i = 0; i < 4; ++i) {
                float xi = ((const float*)&xv[i])[kk];
                acc[i][0] = fmaf(xi, w0, acc[i][0]);
                acc[i][1] = fmaf(xi, w1, acc[i][1]);
                acc[i][2] = fmaf(xi, w2, acc[i][2]);
                acc[i][3] = fmaf(xi, w3, acc[i][3]);
            }
        }
    }

    // reduce the kc pair within each wave (lanes differ in bit 5)
    #pragma unroll
    for (int i = 0; i < 4; ++i)
        #pragma unroll
        for (int j = 0; j < 4; ++j)
            acc[i][j] += __shfl_xor(acc[i][j], 32);
    if ((t & 32) == 0) {
        #pragma unroll
        for (int i = 0; i < 4; ++i) {
            float4 vv = make_float4(acc[i][0], acc[i][1], acc[i][2], acc[i][3]);
            *(float4*)&C[(wv * ROWS + r0 + i) * E + e0] = vv;
        }
    }
    __syncthreads();

    // ---- Phase 3: cross-wave reduce + LN rank-1 correction + clip, write logits ----
    {
        int r   = t >> 5;             // 0..7
        int e0b = (t & 31) * 2;       // 0..62 step 2
        float2 s = make_float2(0.f, 0.f);
        #pragma unroll
        for (int w2 = 0; w2 < 4; ++w2) {
            float2 v = *(float2*)&C[(w2 * ROWS + r) * E + e0b];
            s.x += v.x; s.y += v.y;
        }
        float mu = mu_s[r], rs = rs_s[r];
        float2 cs = *(const float2*)&csum[e0b];
        float2 bs = *(const float2*)&bsum[e0b];
        s.x = rs * (s.x - mu * cs.x) + bs.x;
        s.y = rs * (s.y - mu * cs.y) + bs.y;
        s.x = fminf(fmaxf(s.x, -10.f), 10.f);
        s.y = fminf(fmaxf(s.y, -10.f), 10.f);
        long rg_ = rowBase + r;
        *(float2*)&out[lOff + rg_ * E + e0b] = s;
        *(float2*)&C[r * E + e0b] = s;        // stash clipped logits
    }
    __syncthreads();

    // ---- Phase 4: softmax + top2 per row, wave wv handles rows 2wv, 2wv+1 ----
    #pragma unroll
    for (int rr = 0; rr < 2; ++rr) {
        int r = wv * 2 + rr;
        float l = C[r * E + lane];
        float m = l;
        #pragma unroll
        for (int d = 1; d < 64; d <<= 1) m = fmaxf(m, __shfl_xor(m, d));
        float p = __expf(l - m);
        float ssum = p;
        #pragma unroll
        for (int d = 1; d < 64; d <<= 1) ssum += __shfl_xor(ssum, d);
        float prob = fminf(fmaxf(p / ssum, 1e-4f), 1.0f);

        // top1 (max value, lowest index on tie)
        float v1 = prob; int i1 = lane;
        #pragma unroll
        for (int d = 1; d < 64; d <<= 1) {
            float ov = __shfl_xor(v1, d);
            int   oi = __shfl_xor(i1, d);
            if (ov > v1 || (ov == v1 && oi < i1)) { v1 = ov; i1 = oi; }
        }
        // top2: mask out i1, reduce again
        float v2 = (lane == i1) ? -1.f : prob; int i2 = lane;
        #pragma unroll
        for (int d = 1; d < 64; d <<= 1) {
            float ov = __shfl_xor(v2, d);
            int   oi = __shfl_xor(i2, d);
            if (ov > v2 || (ov == v2 && oi < i2)) { v2 = ov; i2 = oi; }
        }
        if (lane == 0) {
            float ps = fmaxf(v1 + v2, 1e-4f);
            long rg_ = rowBase + r;
            out[rg_ * 2 + 0] = v1 / ps;
            out[rg_ * 2 + 1] = v2 / ps;
            out[iOff + rg_ * 2 + 0] = (float)i1;
            out[iOff + rg_ * 2 + 1] = (float)i2;
        }
    }
}

extern "C" void kernel_launch(void* const* d_in, const int* in_sizes, int n_in,
                              void* d_out, int out_size, void* d_ws, size_t ws_size,
                              hipStream_t stream) {
    const float* X   = (const float*)d_in[0];
    const float* lnw = (const float*)d_in[1];
    const float* lnb = (const float*)d_in[2];
    const float* W   = (const float*)d_in[3];
    float* outp = (float*)d_out;
    float* ws   = (float*)d_ws;

    float* Wt   = ws + WS_WT;
    float* csum = ws + WS_CS;
    float* bsum = ws + WS_BS;

    int N = in_sizes[0] / H;                    // 16384 rows

    prep_transpose<<<(H * E) / 256, 256, 0, stream>>>(W, lnw, Wt);
    prep_sums<<<E, 256, 0, stream>>>(W, lnw, lnb, csum, bsum);
    router_kernel<<<N / ROWS, 256, 0, stream>>>(X, Wt, csum, bsum, outp, N);
}

// Round 3
// 246.583 us; speedup vs baseline: 1.1051x; 1.0893x over previous
//
#include <hip/hip_runtime.h>
#include <math.h>

#define H 2048
#define E 64
#define ROWS 8
#define ST 2052   // xs row stride in floats (16B-aligned, breaks pow2 bank stride)
#define SP 516    // partials slice stride in floats (512 + 4 pad -> kc rotates banks)

// ws layout (floats): Wt'[H*E] | csum[E] | bsum[E]
#define WS_WT   0
#define WS_CS   (H * E)
#define WS_BS   (H * E + E)

__global__ __launch_bounds__(256) void prep_transpose(const float* __restrict__ W,
        const float* __restrict__ lnw, float* __restrict__ Wt) {
    int o = blockIdx.x * 256 + threadIdx.x;   // o = k*64 + e
    int k = o >> 6, e = o & 63;
    Wt[o] = lnw[k] * W[e * H + k];            // coalesced writes, L2-cached reads
}

__global__ __launch_bounds__(256) void prep_sums(const float* __restrict__ W,
        const float* __restrict__ lnw, const float* __restrict__ lnb,
        float* __restrict__ csum, float* __restrict__ bsum) {
    __shared__ float rc[256], rb[256];
    int e = blockIdx.x, t = threadIdx.x;
    float cs = 0.f, bs = 0.f;
    #pragma unroll
    for (int j = 0; j < 8; ++j) {
        int k = t + j * 256;
        float w = W[e * H + k];               // coalesced
        cs += lnw[k] * w;
        bs += lnb[k] * w;
    }
    rc[t] = cs; rb[t] = bs;
    __syncthreads();
    for (int s = 128; s > 0; s >>= 1) {
        if (t < s) { rc[t] += rc[t + s]; rb[t] += rb[t + s]; }
        __syncthreads();
    }
    if (t == 0) { csum[e] = rc[0]; bsum[e] = rb[0]; }
}

__global__ __launch_bounds__(256, 2) void router_kernel(
    const float* __restrict__ X, const float* __restrict__ Wt,
    const float* __restrict__ csum, const float* __restrict__ bsum,
    float* __restrict__ out, int nRows)
{
    // shbuf aliases: phase 1-2: xs[ROWS][ST] raw x rows (16,411 floats used)
    //                phase 3:   partials[32][SP] K-split GEMM partials (16,504 used)
    __shared__ float shbuf[32 * SP];          // 66,048 B
    __shared__ float C2[ROWS * E];            // 2 KB final logits
    __shared__ float mu_s[ROWS], rs_s[ROWS];

    const int t    = threadIdx.x;
    const int lane = t & 63;
    const int wv   = t >> 6;                  // wave id 0..3
    const long rowBase = (long)blockIdx.x * ROWS;
    const long iOff = (long)nRows * 2;        // indices region offset
    const long lOff = (long)nRows * 4;        // logits region offset

    float* xs = shbuf;

    // ---- Phase 1: each wave loads its 2 rows coalesced, stats on the fly ----
    #pragma unroll
    for (int rr = 0; rr < 2; ++rr) {
        int r = wv * 2 + rr;
        const float4* src = (const float4*)(X + (rowBase + r) * H);
        float4 v[8];
        #pragma unroll
        for (int j = 0; j < 8; ++j) v[j] = src[lane + j * 64];
        float s = 0.f, q = 0.f;
        #pragma unroll
        for (int j = 0; j < 8; ++j) {
            s += v[j].x + v[j].y + v[j].z + v[j].w;
            q += v[j].x * v[j].x + v[j].y * v[j].y + v[j].z * v[j].z + v[j].w * v[j].w;
        }
        #pragma unroll
        for (int j = 0; j < 8; ++j)
            *(float4*)&xs[r * ST + ((lane + j * 64) << 2)] = v[j];
        #pragma unroll
        for (int d = 1; d < 64; d <<= 1) {
            s += __shfl_xor(s, d);
            q += __shfl_xor(q, d);
        }
        if (lane == 0) {
            float mu  = s * (1.f / H);
            float var = q * (1.f / H) - mu * mu;
            mu_s[r] = mu;
            rs_s[r] = rsqrtf(var + 1e-5f);
        }
    }
    __syncthreads();

    // ---- Phase 2: GEMM. thread = (eg:8 experts-of-8, kc:32 K-slices of 64) ----
    // Every thread covers all 8 rows -> each Wt element read once per block.
    // j-order rotated per kcl so the 8 broadcast x addresses hit distinct bank-quads.
    const int eg  = t & 7;
    const int kc  = t >> 3;                   // 0..31
    const int kcl = kc & 7;
    const int e0  = eg * 8;
    const int kbase = kc * 64;
    const float4* Wt4 = (const float4*)Wt;

    float4 acc[8][2];
    #pragma unroll
    for (int r = 0; r < 8; ++r) {
        acc[r][0] = make_float4(0.f, 0.f, 0.f, 0.f);
        acc[r][1] = make_float4(0.f, 0.f, 0.f, 0.f);
    }

    float4 wA[8], wB[8];
    auto ldW = [&](int jj, float4* wbuf) {
        int jp = (jj + kcl * 2) & 15;
        int k  = kbase + jp * 4;
        const float4* wp = Wt4 + k * 16 + eg * 2;  // &Wt[k*E + e0]
        #pragma unroll
        for (int kk = 0; kk < 4; ++kk) {
            wbuf[kk * 2]     = wp[kk * 16];
            wbuf[kk * 2 + 1] = wp[kk * 16 + 1];
        }
    };
    auto fmaStep = [&](int jj, const float4* wbuf) {
        int jp = (jj + kcl * 2) & 15;
        int k  = kbase + jp * 4;
        float4 xv[8];
        #pragma unroll
        for (int r = 0; r < 8; ++r)
            xv[r] = *(float4*)&xs[r * ST + k];
        #pragma unroll
        for (int kk = 0; kk < 4; ++kk) {
            float4 w0 = wbuf[kk * 2], w1 = wbuf[kk * 2 + 1];
            #pragma unroll
            for (int r = 0; r < 8; ++r) {
                float xi = ((const float*)&xv[r])[kk];
                acc[r][0].x = fmaf(xi, w0.x, acc[r][0].x);
                acc[r][0].y = fmaf(xi, w0.y, acc[r][0].y);
                acc[r][0].z = fmaf(xi, w0.z, acc[r][0].z);
                acc[r][0].w = fmaf(xi, w0.w, acc[r][0].w);
                acc[r][1].x = fmaf(xi, w1.x, acc[r][1].x);
                acc[r][1].y = fmaf(xi, w1.y, acc[r][1].y);
                acc[r][1].z = fmaf(xi, w1.z, acc[r][1].z);
                acc[r][1].w = fmaf(xi, w1.w, acc[r][1].w);
            }
        }
    };

    ldW(0, wA);
    for (int j = 0; j < 16; j += 2) {
        ldW(j + 1, wB);
        fmaStep(j, wA);
        ldW((j + 2) & 15, wA);   // last iter: harmless redundant load
        fmaStep(j + 1, wB);
    }

    // ---- Phase 3: K-split reduction through LDS (aliases dead xs) ----
    __syncthreads();                          // all xs reads complete
    float* part = shbuf;
    #pragma unroll
    for (int r = 0; r < 8; ++r) {
        *(float4*)&part[kc * SP + r * 64 + e0]     = acc[r][0];
        *(float4*)&part[kc * SP + r * 64 + e0 + 4] = acc[r][1];
    }
    __syncthreads();

    if (t < 128) {
        int r = t >> 4, ef4 = t & 15;
        float4 s = make_float4(0.f, 0.f, 0.f, 0.f);
        #pragma unroll
        for (int k2 = 0; k2 < 32; ++k2) {
            float4 v = *(float4*)&part[k2 * SP + r * 64 + ef4 * 4];
            s.x += v.x; s.y += v.y; s.z += v.z; s.w += v.w;
        }
        // LN rank-1 correction + clip
        float mu = mu_s[r], rs = rs_s[r];
        float4 cs = *(const float4*)&csum[ef4 * 4];
        float4 bs = *(const float4*)&bsum[ef4 * 4];
        s.x = fminf(fmaxf(rs * (s.x - mu * cs.x) + bs.x, -10.f), 10.f);
        s.y = fminf(fmaxf(rs * (s.y - mu * cs.y) + bs.y, -10.f), 10.f);
        s.z = fminf(fmaxf(rs * (s.z - mu * cs.z) + bs.z, -10.f), 10.f);
        s.w = fminf(fmaxf(rs * (s.w - mu * cs.w) + bs.w, -10.f), 10.f);
        long rg_ = rowBase + r;
        *(float4*)&out[lOff + rg_ * E + ef4 * 4] = s;
        *(float4*)&C2[r * E + ef4 * 4] = s;
    }
    __syncthreads();

    // ---- Phase 4: softmax + top2 per row, wave wv handles rows 2wv, 2wv+1 ----
    #pragma unroll
    for (int rr = 0; rr < 2; ++rr) {
        int r = wv * 2 + rr;
        float l = C2[r * E + lane];
        float m = l;
        #pragma unroll
        for (int d = 1; d < 64; d <<= 1) m = fmaxf(m, __shfl_xor(m, d));
        float p = __expf(l - m);
        float ssum = p;
        #pragma unroll
        for (int d = 1; d < 64; d <<= 1) ssum += __shfl_xor(ssum, d);
        float prob = fminf(fmaxf(p / ssum, 1e-4f), 1.0f);

        // top1 (max value, lowest index on tie)
        float v1 = prob; int i1 = lane;
        #pragma unroll
        for (int d = 1; d < 64; d <<= 1) {
            float ov = __shfl_xor(v1, d);
            int   oi = __shfl_xor(i1, d);
            if (ov > v1 || (ov == v1 && oi < i1)) { v1 = ov; i1 = oi; }
        }
        // top2: mask out i1, reduce again
        float v2 = (lane == i1) ? -1.f : prob; int i2 = lane;
        #pragma unroll
        for (int d = 1; d < 64; d <<= 1) {
            float ov = __shfl_xor(v2, d);
            int   oi = __shfl_xor(i2, d);
            if (ov > v2 || (ov == v2 && oi < i2)) { v2 = ov; i2 = oi; }
        }
        if (lane == 0) {
            float ps = fmaxf(v1 + v2, 1e-4f);
            long rg_ = rowBase + r;
            out[rg_ * 2 + 0] = v1 / ps;
            out[rg_ * 2 + 1] = v2 / ps;
            out[iOff + rg_ * 2 + 0] = (float)i1;
            out[iOff + rg_ * 2 + 1] = (float)i2;
        }
    }
}

extern "C" void kernel_launch(void* const* d_in, const int* in_sizes, int n_in,
                              void* d_out, int out_size, void* d_ws, size_t ws_size,
                              hipStream_t stream) {
    const float* X   = (const float*)d_in[0];
    const float* lnw = (const float*)d_in[1];
    const float* lnb = (const float*)d_in[2];
    const float* W   = (const float*)d_in[3];
    float* outp = (float*)d_out;
    float* ws   = (float*)d_ws;

    float* Wt   = ws + WS_WT;
    float* csum = ws + WS_CS;
    float* bsum = ws + WS_BS;

    int N = in_sizes[0] / H;                    // 16384 rows

    prep_transpose<<<(H * E) / 256, 256, 0, stream>>>(W, lnw, Wt);
    prep_sums<<<E, 256, 0, stream>>>(W, lnw, lnb, csum, bsum);
    router_kernel<<<N / ROWS, 256, 0, stream>>>(X, Wt, csum, bsum, outp, N);
}